// Round 10
// baseline (48.366 us; speedup 1.0000x reference)
//
#include <hip/hip_runtime.h>
#include <hip/hip_fp16.h>
#include <float.h>

constexpr int KMAX = 11;   // KS_MAX
constexpr int SEQ  = 512;  // SEQ_LEN
constexpr int NB   = 64;   // BATCH
constexpr int NBB  = 8;    // batches per main block
constexpr int NGRP = NB / NBB;
constexpr int MSTR = 32;   // meta ints/k: [0]=nj [1..11]=c [12..22]=w2 [23]=cmin [24]=cmax [25]=bin
constexpr int KPB  = 2;    // kernels per main block (stage amortization)
constexpr int WS0  = 1088; // bin0 window slots (slot = s;     cmin>=0, lout+63+cmax<1088)
constexpr int WS1  = 2112; // bin1 window slots (slot = s+512; covers s in [-510, 1596])

__device__ __forceinline__ unsigned h2b(__half2 h) { unsigned u; __builtin_memcpy(&u, &h, 4); return u; }
__device__ __forceinline__ __half2  b2h(unsigned u) { __half2 h; __builtin_memcpy(&h, &u, 4); return h; }

__device__ __forceinline__ unsigned pkmax(unsigned a, unsigned b) {
    unsigned d; asm("v_pk_max_f16 %0, %1, %2" : "=v"(d) : "v"(a), "v"(b)); return d;
}
__device__ __forceinline__ unsigned pkadd(unsigned a, unsigned b) { return h2b(__hadd2(b2h(a), b2h(b))); }
__device__ __forceinline__ __half2 h2max(__half2 a, __half2 b) { return b2h(pkmax(h2b(a), h2b(b))); }
// fused (a*b+c) clamped to [0,1] — whole count update in one VOP3P
__device__ __forceinline__ unsigned pkfma_clamp(unsigned a, unsigned b, unsigned c) {
    unsigned d; asm("v_pk_fma_f16 %0, %1, %2, %3 clamp" : "=v"(d) : "v"(a), "v"(b), "v"(c)); return d;
}

template<int CTRL>
__device__ __forceinline__ unsigned dppmov(unsigned old, unsigned v) {
    return (unsigned)__builtin_amdgcn_update_dpp((int)old, (int)v, CTRL, 0xF, 0xF, false);
}
constexpr unsigned NEGINF2 = 0xFC00FC00u;   // f16 -inf pair

__device__ __forceinline__ unsigned dpp_redmax(unsigned x) {
    x = pkmax(x, dppmov<0xB1 >(NEGINF2, x));
    x = pkmax(x, dppmov<0x4E >(NEGINF2, x));
    x = pkmax(x, dppmov<0x141>(NEGINF2, x));
    x = pkmax(x, dppmov<0x140>(NEGINF2, x));
    x = pkmax(x, dppmov<0x142>(NEGINF2, x));
    x = pkmax(x, dppmov<0x143>(NEGINF2, x));
    return x;                                  // lane 63 valid
}
__device__ __forceinline__ unsigned dpp_redadd(unsigned x) {
    x = pkadd(x, dppmov<0xB1 >(0u, x));
    x = pkadd(x, dppmov<0x4E >(0u, x));
    x = pkadd(x, dppmov<0x141>(0u, x));
    x = pkadd(x, dppmov<0x140>(0u, x));
    x = pkadd(x, dppmov<0x142>(0u, x));
    x = pkadd(x, dppmov<0x143>(0u, x));
    return x;                                  // lane 63 valid
}

// ======================= prep kernel =======================
__global__ __launch_bounds__(256)
void prep_kernel(const float* __restrict__ x, const float* __restrict__ w,
                 const int* __restrict__ idx, const int* __restrict__ l_out,
                 int* __restrict__ meta, unsigned short* __restrict__ xt,
                 int K, int maxL)
{
    const int tid = threadIdx.x;
    if ((int)blockIdx.x >= K) {
        const int j  = ((int)blockIdx.x - K) * 256 + tid;   // 0..8191
        const int b  = j >> 7, s4 = j & 127;
        const float4 v = reinterpret_cast<const float4*>(x)[b * (SEQ / 4) + s4];
        const int g = b >> 3, bl = b & 7;
        unsigned short* dst = xt + ((size_t)g * SEQ + s4 * 4) * NBB + bl;
        __half h;
        h = __float2half_rn(v.x); __builtin_memcpy(&dst[0 * NBB], &h, 2);
        h = __float2half_rn(v.y); __builtin_memcpy(&dst[1 * NBB], &h, 2);
        h = __float2half_rn(v.z); __builtin_memcpy(&dst[2 * NBB], &h, 2);
        h = __float2half_rn(v.w); __builtin_memcpy(&dst[3 * NBB], &h, 2);
        return;
    }

    __shared__ int c_sh[KMAX];
    const int k = blockIdx.x, wave = tid >> 6, lane = tid & 63;

    // idx[k,j,t] = clip(t+c, 0, 511): interior value (0<v<511) gives c = v - t.
    for (int j = wave; j < KMAX; j += 4) {
        const int* row = idx + ((size_t)k * KMAX + j) * (size_t)maxL;
        int c = 0;   // fallback: c=0 with w=0 contributes exactly 0
        {
            const int t = min(lane * 16, maxL - 1);   // strided probe: interior run >= 510 wide
            const int v = row[t];
            const bool interior = (v > 0) && (v < SEQ - 1);
            const unsigned long long mb = __ballot(interior);
            if (mb != 0ull) {
                const int fl = __builtin_ctzll(mb);
                c = __shfl(v, fl) - min(fl * 16, maxL - 1);
            } else {
                for (int base = 0; base < maxL; base += 64) {
                    const int t2 = base + lane;
                    const int v2 = (t2 < maxL) ? row[t2] : 0;
                    const bool in2 = (v2 > 0) && (v2 < SEQ - 1);
                    const unsigned long long mb2 = __ballot(in2);
                    if (mb2 != 0ull) {
                        const int fl2 = __builtin_ctzll(mb2);
                        c = __shfl(v2, fl2) - (base + fl2);
                        break;
                    }
                }
            }
        }
        if (lane == 0) c_sh[j] = c;
    }
    __syncthreads();

    if (tid == 0) {
        int* mk = meta + (size_t)k * MSTR;
        int n = 0, cmin = 0, cmax = 0;
        for (int j = 0; j < KMAX; ++j) {
            const float wj = w[(size_t)k * KMAX + j];
            if (wj != 0.0f) {
                const int c = c_sh[j];
                mk[1 + n] = c;
                __half hw = __float2half_rn(wj);
                unsigned short ub; __builtin_memcpy(&ub, &hw, 2);
                mk[12 + n] = (unsigned)ub | ((unsigned)ub << 16);
                if (n == 0) { cmin = c; cmax = c; }
                else { cmin = min(cmin, c); cmax = max(cmax, c); }
                ++n;
            }
        }
        for (int jj = n; jj < KMAX; ++jj) { mk[1 + jj] = 0; mk[12 + jj] = 0; }  // in-window, w=0
        const int lo = l_out[k];
        mk[0]  = n;
        mk[23] = cmin;
        mk[24] = cmax;
        mk[25] = (cmin >= 0 && (lo + 63 + cmax) < WS0) ? 0 : 1;   // bin select
    }
}

// ======================= binsort: LPT permutation per bin =======================
// counting sort by (bin, descending lout bucket). Output order within a bucket is
// atomic-race arbitrary, but outputs are invariant under perm (pure scheduling).
__global__ __launch_bounds__(256)
void binsort_kernel(const int* __restrict__ meta, const int* __restrict__ l_out,
                    int* __restrict__ perm, int* __restrict__ counts, int K)
{
    __shared__ int hist[34], base[34];
    const int tid = threadIdx.x;
    if (tid < 34) hist[tid] = 0;
    __syncthreads();
    for (int k = tid; k < K; k += 256) {
        const int bucket = meta[(size_t)k * MSTR + 25] * 17 + (16 - min(16, l_out[k] >> 6));
        atomicAdd(&hist[bucket], 1);
    }
    __syncthreads();
    if (tid == 0) {
        int run = 0;
        for (int b = 0; b < 34; ++b) { base[b] = run; run += hist[b]; }
        int c0 = 0;
        for (int b = 0; b < 17; ++b) c0 += hist[b];
        counts[0] = c0;
        counts[1] = K - c0;
    }
    __syncthreads();
    for (int k = tid; k < K; k += 256) {
        const int bucket = meta[(size_t)k * MSTR + 25] * 17 + (16 - min(16, l_out[k] >> 6));
        perm[atomicAdd(&base[bucket], 1)] = k;
    }
}

// ======================= main kernel =======================
// grid (ceil(K/KPB), 8). Fixed k-independent zero-fringed window staged ONCE,
// then KPB kernels convolved branchlessly (R8 body). No per-k LDS re-staging.
template<int NJ>
__device__ __forceinline__ void conv_body(
    const char* __restrict__ xsc, const int* __restrict__ mk,
    int lout, int sbase, int wave, int lane, unsigned ctermb,
    __half2 (&mx2)[4], __half2 (&ct2)[4])
{
    const __half2 zero2 = __float2half2_rn(0.f);
    const __half2 nbig2 = __float2half2_rn(-65504.f);
    const unsigned C4b  = 0x74007400u;   // f16 pair {2^14, 2^14}

    int addr[NJ]; __half2 wr[NJ];
#pragma unroll
    for (int j = 0; j < NJ; ++j) {
        const int c = __builtin_amdgcn_readfirstlane(mk[1 + j]);
        wr[j]   = b2h((unsigned)__builtin_amdgcn_readfirstlane(mk[12 + j]));
        addr[j] = (sbase + wave * 64 + lane + c) * 16;
    }
#pragma unroll
    for (int m = 0; m < 4; ++m) { mx2[m] = nbig2; ct2[m] = zero2; }

#pragma unroll
    for (int it = 0; it < 4; ++it) {
        const int tb = wave * 64 + it * 256;
        if (tb + 64 <= lout) {             // wave-uniform SALU guard
            uint4 d[NJ];
#pragma unroll
            for (int j = 0; j < NJ; ++j)
                d[j] = *reinterpret_cast<const uint4*>(xsc + addr[j] + it * 4096);
            __half2 a4[4] = {zero2, zero2, zero2, zero2};
#pragma unroll
            for (int j = 0; j < NJ; ++j) {
                a4[0] = __hfma2(wr[j], b2h(d[j].x), a4[0]);
                a4[1] = __hfma2(wr[j], b2h(d[j].y), a4[1]);
                a4[2] = __hfma2(wr[j], b2h(d[j].z), a4[2]);
                a4[3] = __hfma2(wr[j], b2h(d[j].w), a4[3]);
            }
#pragma unroll
            for (int m = 0; m < 4; ++m) {
                mx2[m] = h2max(mx2[m], a4[m]);
                ct2[m] = b2h(pkadd(h2b(ct2[m]), pkfma_clamp(h2b(a4[m]), C4b, ctermb)));
            }
        }
    }

    const int rem = lout & 63;
    if (rem) {                              // straddle chunk, owned by wave pc&3
        const int pc = lout >> 6;
        if ((pc & 3) == wave) {
            const int off = (pc >> 2) << 12;
            uint4 d[NJ];
#pragma unroll
            for (int j = 0; j < NJ; ++j)
                d[j] = *reinterpret_cast<const uint4*>(xsc + addr[j] + off);
            __half2 a4[4] = {zero2, zero2, zero2, zero2};
#pragma unroll
            for (int j = 0; j < NJ; ++j) {
                a4[0] = __hfma2(wr[j], b2h(d[j].x), a4[0]);
                a4[1] = __hfma2(wr[j], b2h(d[j].y), a4[1]);
                a4[2] = __hfma2(wr[j], b2h(d[j].z), a4[2]);
                a4[3] = __hfma2(wr[j], b2h(d[j].w), a4[3]);
            }
            const bool tm = lane < rem;
#pragma unroll
            for (int m = 0; m < 4; ++m) {
                a4[m] = tm ? a4[m] : nbig2;   // -65504*2^14 -> -inf -> clamp -> 0
                mx2[m] = h2max(mx2[m], a4[m]);
                ct2[m] = b2h(pkadd(h2b(ct2[m]), pkfma_clamp(h2b(a4[m]), C4b, ctermb)));
            }
        }
    }
}

template<int WS, int SBASE, int BIN, int MINW>
__global__ __launch_bounds__(256, MINW)
void rocket_main(const unsigned short* __restrict__ xt, const int* __restrict__ meta,
                 const float* __restrict__ bias, const int* __restrict__ l_out,
                 const int* __restrict__ perm, const int* __restrict__ counts,
                 float* __restrict__ out, int K)
{
    __shared__ __align__(16) unsigned xs_u[WS * 4];
    __shared__ unsigned redm[KPB][4][4], redc[KPB][4][4];

    const int cnt = counts[BIN];
    const int i0  = (int)blockIdx.x * KPB;
    if (i0 >= cnt) return;
    const int pbase = BIN ? counts[0] : 0;
    const int grp   = blockIdx.y;
    const int tid   = threadIdx.x;
    const int wave  = __builtin_amdgcn_readfirstlane(tid >> 6);
    const int lane  = tid & 63;

    // ---- stage fixed window once: zeros outside s in [0,512), data inside ----
    float4* xs4 = reinterpret_cast<float4*>(xs_u);
    const float4* src = reinterpret_cast<const float4*>(xt) + (size_t)grp * SEQ;
#pragma unroll
    for (int ib = 0; ib < WS; ib += 256) {
        const int i = ib + tid;
        if (i < WS) {
            const int s = i - SBASE;
            float4 v = make_float4(0.f, 0.f, 0.f, 0.f);
            if ((unsigned)s < (unsigned)SEQ) v = src[s];
            xs4[i] = v;
        }
    }
    __syncthreads();

    const char* xsc = reinterpret_cast<const char*>(xs_u);
#pragma unroll
    for (int kk = 0; kk < KPB; ++kk) {
        const int i = i0 + kk;
        if (i < cnt) {
            const int  k  = perm[pbase + i];
            const int* mk = meta + (size_t)k * MSTR;
            const int  nj   = __builtin_amdgcn_readfirstlane(mk[0]);
            const int  lout = l_out[k];
            const unsigned ctermb = h2b(__float2half2_rn(bias[k] * 16384.f));
            __half2 mx2[4], ct2[4];
            if (nj <= 7)      conv_body<7 >(xsc, mk, lout, SBASE, wave, lane, ctermb, mx2, ct2);
            else if (nj <= 9) conv_body<9 >(xsc, mk, lout, SBASE, wave, lane, ctermb, mx2, ct2);
            else              conv_body<11>(xsc, mk, lout, SBASE, wave, lane, ctermb, mx2, ct2);
            unsigned um[4], uc[4];
#pragma unroll
            for (int m = 0; m < 4; ++m) { um[m] = dpp_redmax(h2b(mx2[m])); uc[m] = dpp_redadd(h2b(ct2[m])); }
            if (lane == 63) {
#pragma unroll
                for (int m = 0; m < 4; ++m) { redm[kk][wave][m] = um[m]; redc[kk][wave][m] = uc[m]; }
            }
        }
    }
    __syncthreads();

    if (tid < 16 * KPB) {
        const int kk = tid >> 4;
        const int i  = i0 + kk;
        if (i < cnt) {
            const int k  = perm[pbase + i];
            const int t  = tid & 15;
            const int bl = t >> 1, kind = t & 1;       // batch-in-group, {max,ppv}
            const int m  = bl >> 1, hi = bl & 1;
            const int b  = grp * NBB + bl;
            if (kind == 0) {
                float v = -FLT_MAX;
#pragma unroll
                for (int wv = 0; wv < 4; ++wv) {
                    const __half2 h = b2h(redm[kk][wv][m]);
                    v = fmaxf(v, hi ? __high2float(h) : __low2float(h));
                }
                out[(size_t)b * (2 * K) + 2 * k] = v + bias[k];   // deferred bias
            } else {
                float s = 0.f;
#pragma unroll
                for (int wv = 0; wv < 4; ++wv) {
                    const __half2 h = b2h(redc[kk][wv][m]);
                    s += hi ? __high2float(h) : __low2float(h);
                }
                out[(size_t)b * (2 * K) + 2 * k + 1] = s / (float)l_out[k];
            }
        }
    }
}

// ======================= launch =======================
extern "C" void kernel_launch(void* const* d_in, const int* in_sizes, int n_in,
                              void* d_out, int out_size, void* d_ws, size_t ws_size,
                              hipStream_t stream)
{
    const float* x    = (const float*)d_in[0];
    const float* w    = (const float*)d_in[1];
    const float* bias = (const float*)d_in[2];
    const int*   idx  = (const int*)d_in[3];
    // d_in[4] = valid (unused: validity derived exactly from the idx ramp)
    const int*   lout = (const int*)d_in[5];
    float* out = (float*)d_out;

    const int K    = in_sizes[2];               // N_KERNELS
    const int maxL = in_sizes[3] / (K * KMAX);  // idx = [K][KMAX][maxL]

    // workspace: meta | xt16 | perm | counts (256B-aligned splits)
    char* wsp = (char*)d_ws;
    int* meta = (int*)wsp;
    size_t o1 = ((size_t)K * MSTR * sizeof(int) + 255) & ~(size_t)255;
    unsigned short* xt = (unsigned short*)(wsp + o1);
    size_t o2 = o1 + (((size_t)NB * SEQ * 2 + 255) & ~(size_t)255);
    int* perm = (int*)(wsp + o2);
    size_t o3 = o2 + (((size_t)K * sizeof(int) + 255) & ~(size_t)255);
    int* counts = (int*)(wsp + o3);

    const int nblk = (K + KPB - 1) / KPB;
    prep_kernel<<<K + 32, 256, 0, stream>>>(x, w, idx, lout, meta, xt, K, maxL);
    binsort_kernel<<<1, 256, 0, stream>>>(meta, lout, perm, counts, K);
    rocket_main<WS0,   0, 0, 8><<<dim3(nblk, NGRP), 256, 0, stream>>>(xt, meta, bias, lout, perm, counts, out, K);
    rocket_main<WS1, 512, 1, 4><<<dim3(nblk, NGRP), 256, 0, stream>>>(xt, meta, bias, lout, perm, counts, out, K);
}

// Round 11
// 37.563 us; speedup vs baseline: 1.2876x; 1.2876x over previous
//
#include <hip/hip_runtime.h>
#include <hip/hip_fp16.h>
#include <float.h>

constexpr int KMAX  = 11;    // KS_MAX
constexpr int SEQ   = 512;   // SEQ_LEN
constexpr int NB    = 64;    // BATCH
constexpr int NBB   = 8;     // batches per main block (8 groups)
constexpr int NGRP  = NB / NBB;
constexpr int MSTR  = 32;    // meta ints per k: [0]=nj [1..11]=c [12..22]=w2bits [23]=cmin [24]=cmax
constexpr int WSLOT = 1600;  // LDS window slots, 16 B (8 f16) each; slot = s - cmin
                             // span proof: lout+63+(cmax-cmin) <= 1022+63+510 = 1595 < 1600

__device__ __forceinline__ unsigned h2b(__half2 h) { unsigned u; __builtin_memcpy(&u, &h, 4); return u; }
__device__ __forceinline__ __half2  b2h(unsigned u) { __half2 h; __builtin_memcpy(&h, &u, 4); return h; }

// ROCm 7.2 has no __hmax2/__hmin2 — use VOP3P directly.
__device__ __forceinline__ unsigned pkmax(unsigned a, unsigned b) {
    unsigned d; asm("v_pk_max_f16 %0, %1, %2" : "=v"(d) : "v"(a), "v"(b)); return d;
}
__device__ __forceinline__ unsigned pkadd(unsigned a, unsigned b) { return h2b(__hadd2(b2h(a), b2h(b))); }
__device__ __forceinline__ __half2 h2max(__half2 a, __half2 b) { return b2h(pkmax(h2b(a), h2b(b))); }
// fused (a*b+c) clamped to [0,1] — the whole count update in one VOP3P
__device__ __forceinline__ unsigned pkfma_clamp(unsigned a, unsigned b, unsigned c) {
    unsigned d; asm("v_pk_fma_f16 %0, %1, %2, %3 clamp" : "=v"(d) : "v"(a), "v"(b), "v"(c)); return d;
}

// DPP lane-exchange (VALU pipe, no LDS). Masked-out rows get `old` (identity).
template<int CTRL>
__device__ __forceinline__ unsigned dppmov(unsigned old, unsigned v) {
    return (unsigned)__builtin_amdgcn_update_dpp((int)old, (int)v, CTRL, 0xF, 0xF, false);
}
constexpr unsigned NEGINF2 = 0xFC00FC00u;   // -inf | -inf (f16 pair)

__device__ __forceinline__ unsigned dpp_redmax(unsigned x) {
    x = pkmax(x, dppmov<0xB1 >(NEGINF2, x));  // quad_perm xor1
    x = pkmax(x, dppmov<0x4E >(NEGINF2, x));  // quad_perm xor2
    x = pkmax(x, dppmov<0x141>(NEGINF2, x));  // row_half_mirror
    x = pkmax(x, dppmov<0x140>(NEGINF2, x));  // row_mirror
    x = pkmax(x, dppmov<0x142>(NEGINF2, x));  // row_bcast15
    x = pkmax(x, dppmov<0x143>(NEGINF2, x));  // row_bcast31
    return x;                                  // lane 63 valid
}
__device__ __forceinline__ unsigned dpp_redadd(unsigned x) {
    x = pkadd(x, dppmov<0xB1 >(0u, x));
    x = pkadd(x, dppmov<0x4E >(0u, x));
    x = pkadd(x, dppmov<0x141>(0u, x));
    x = pkadd(x, dppmov<0x140>(0u, x));
    x = pkadd(x, dppmov<0x142>(0u, x));
    x = pkadd(x, dppmov<0x143>(0u, x));
    return x;                                  // lane 63 valid
}

// ======================= prep kernel =======================
// blocks [0, K):    derive c_kj from idx ramp (strided probe, loads hoisted so a
//                   wave's <=3 probe reads are in flight together), compact taps.
// blocks [K, K+32): transpose+convert x (NB x SEQ f32) -> xt16[g][s][8] f16
__global__ __launch_bounds__(256)
void prep_kernel(const float* __restrict__ x, const float* __restrict__ w,
                 const int* __restrict__ idx, int* __restrict__ meta,
                 unsigned short* __restrict__ xt, int K, int maxL)
{
    const int tid = threadIdx.x;
    if ((int)blockIdx.x >= K) {
        const int j  = ((int)blockIdx.x - K) * 256 + tid;   // 0..8191
        const int b  = j >> 7, s4 = j & 127;
        const float4 v = reinterpret_cast<const float4*>(x)[b * (SEQ / 4) + s4];
        const int g = b >> 3, bl = b & 7;
        unsigned short* dst = xt + ((size_t)g * SEQ + s4 * 4) * NBB + bl;
        __half h;
        h = __float2half_rn(v.x); __builtin_memcpy(&dst[0 * NBB], &h, 2);
        h = __float2half_rn(v.y); __builtin_memcpy(&dst[1 * NBB], &h, 2);
        h = __float2half_rn(v.z); __builtin_memcpy(&dst[2 * NBB], &h, 2);
        h = __float2half_rn(v.w); __builtin_memcpy(&dst[3 * NBB], &h, 2);
        return;
    }

    __shared__ int c_sh[KMAX];
    const int k = blockIdx.x, wave = tid >> 6, lane = tid & 63;

    // idx[k,j,t] = clip(t+c, 0, 511): interior value (0<v<511) gives c = v - t.
    // Strided probe t = 0,16,...,1008 (clamped): every tap's interior set contains
    // a sampled point (runs >=510 wide, or clamp hits the short run at the edges).
    const int tprobe = min(lane * 16, maxL - 1);
    int vv[3] = {0, 0, 0};
#pragma unroll
    for (int i = 0; i < 3; ++i) {                 // issue all probe loads together
        const int j = wave + i * 4;
        if (j < KMAX) vv[i] = idx[((size_t)k * KMAX + j) * (size_t)maxL + tprobe];
    }
#pragma unroll
    for (int i = 0; i < 3; ++i) {
        const int j = wave + i * 4;               // wave-uniform -> no divergent ballot
        if (j < KMAX) {
            int c = 0;                             // fallback: c=0 (in-window, w=0 -> 0)
            const bool interior = (vv[i] > 0) && (vv[i] < SEQ - 1);
            const unsigned long long mb = __ballot(interior);
            if (mb != 0ull) {
                const int fl = __builtin_ctzll(mb);
                c = __shfl(vv[i], fl) - min(fl * 16, maxL - 1);
            } else {                               // degenerate: dense 64-wide scan
                const int* row = idx + ((size_t)k * KMAX + j) * (size_t)maxL;
                for (int base = 0; base < maxL; base += 64) {
                    const int t2 = base + lane;
                    const int v2 = (t2 < maxL) ? row[t2] : 0;
                    const bool in2 = (v2 > 0) && (v2 < SEQ - 1);
                    const unsigned long long mb2 = __ballot(in2);
                    if (mb2 != 0ull) {
                        const int fl2 = __builtin_ctzll(mb2);
                        c = __shfl(v2, fl2) - (base + fl2);
                        break;
                    }
                }
            }
            if (lane == 0) c_sh[j] = c;
        }
    }
    __syncthreads();

    if (tid == 0) {
        int* mk = meta + (size_t)k * MSTR;
        int n = 0, cmin = 0, cmax = 0;
        for (int j = 0; j < KMAX; ++j) {
            const float wj = w[(size_t)k * KMAX + j];
            if (wj != 0.0f) {
                const int c = c_sh[j];
                mk[1 + n] = c;
                __half hw = __float2half_rn(wj);
                unsigned short ub; __builtin_memcpy(&ub, &hw, 2);
                mk[12 + n] = (unsigned)ub | ((unsigned)ub << 16);
                cmin = min(cmin, c); cmax = max(cmax, c);   // tap j=0 has c<=0 -> cmin<=0
                ++n;
            }
        }
        for (int jj = n; jj < KMAX; ++jj) { mk[1 + jj] = 0; mk[12 + jj] = 0; }  // in-window, w=0
        mk[0]  = n;
        mk[23] = cmin;
        mk[24] = cmax;
    }
}

// ======================= main kernel =======================
// grid (K, 8): block = (kernel k, 8-batch group). 256 threads = 4 waves.
// LDS window: slot = s - cmin, 8 f16 batches per slot (16 B). Zeros outside x's
// [0,512) range => out-of-range taps contribute exactly 0 (== reference's mask).
// Branchless conv (R8): chunk ic handled by wave ic&3 at unroll step ic>>2; all
// NJ ds_read_b128 issue back-to-back with compile-time offset immediates.
// Tap meta (c, w) read via wave-uniform GLOBAL pointer + readfirstlane — zero
// LDS traffic for meta (was ~30% of the DS pipe). Reductions on VALU via DPP.
template<int NJ>
__device__ __forceinline__ void conv_body(
    const char* __restrict__ xsc, const int* __restrict__ mk,
    int lout, int x0, int wave, int lane, unsigned ctermb,
    __half2 (&mx2)[4], __half2 (&ct2)[4])
{
    const __half2 zero2 = __float2half2_rn(0.f);
    const __half2 nbig2 = __float2half2_rn(-65504.f);
    const unsigned C4b  = 0x74007400u;   // f16 pair {2^14, 2^14}

    int addr[NJ]; __half2 wr[NJ];
#pragma unroll
    for (int j = 0; j < NJ; ++j) {
        const int c = __builtin_amdgcn_readfirstlane(mk[1 + j]);
        wr[j]   = b2h((unsigned)__builtin_amdgcn_readfirstlane(mk[12 + j]));
        addr[j] = (wave * 64 + lane + c + x0) * 16;
    }
#pragma unroll
    for (int m = 0; m < 4; ++m) { mx2[m] = nbig2; ct2[m] = zero2; }

#pragma unroll
    for (int it = 0; it < 4; ++it) {
        const int tb = wave * 64 + it * 256;
        if (tb + 64 <= lout) {             // wave-uniform SALU guard, full chunk
            uint4 d[NJ];
#pragma unroll
            for (int j = 0; j < NJ; ++j)
                d[j] = *reinterpret_cast<const uint4*>(xsc + addr[j] + it * 4096);
            __half2 a4[4] = {zero2, zero2, zero2, zero2};
#pragma unroll
            for (int j = 0; j < NJ; ++j) {
                a4[0] = __hfma2(wr[j], b2h(d[j].x), a4[0]);
                a4[1] = __hfma2(wr[j], b2h(d[j].y), a4[1]);
                a4[2] = __hfma2(wr[j], b2h(d[j].z), a4[2]);
                a4[3] = __hfma2(wr[j], b2h(d[j].w), a4[3]);
            }
#pragma unroll
            for (int m = 0; m < 4; ++m) {
                mx2[m] = h2max(mx2[m], a4[m]);
                ct2[m] = b2h(pkadd(h2b(ct2[m]), pkfma_clamp(h2b(a4[m]), C4b, ctermb)));
            }
        }
    }

    const int rem = lout & 63;
    if (rem) {                              // straddle chunk pc, owned by wave pc&3
        const int pc = lout >> 6;
        if ((pc & 3) == wave) {
            const int off = (pc >> 2) << 12;
            uint4 d[NJ];
#pragma unroll
            for (int j = 0; j < NJ; ++j)
                d[j] = *reinterpret_cast<const uint4*>(xsc + addr[j] + off);
            __half2 a4[4] = {zero2, zero2, zero2, zero2};
#pragma unroll
            for (int j = 0; j < NJ; ++j) {
                a4[0] = __hfma2(wr[j], b2h(d[j].x), a4[0]);
                a4[1] = __hfma2(wr[j], b2h(d[j].y), a4[1]);
                a4[2] = __hfma2(wr[j], b2h(d[j].z), a4[2]);
                a4[3] = __hfma2(wr[j], b2h(d[j].w), a4[3]);
            }
            const bool tm = lane < rem;
#pragma unroll
            for (int m = 0; m < 4; ++m) {
                a4[m] = tm ? a4[m] : nbig2;   // -65504*2^14 -> -inf -> clamp -> 0
                mx2[m] = h2max(mx2[m], a4[m]);
                ct2[m] = b2h(pkadd(h2b(ct2[m]), pkfma_clamp(h2b(a4[m]), C4b, ctermb)));
            }
        }
    }
}

__global__ __launch_bounds__(256, 6)
void rocket_main(const unsigned short* __restrict__ xt, const int* __restrict__ meta,
                 const float* __restrict__ bias, const int* __restrict__ l_out,
                 float* __restrict__ out, int K)
{
    __shared__ __align__(16) unsigned xs_u[WSLOT * 4];   // 25600 B window
    __shared__ __align__(16) unsigned redm[4][4], redc[4][4];

    const int k    = blockIdx.x;
    const int grp  = blockIdx.y;
    const int tid  = threadIdx.x;
    const int wave = __builtin_amdgcn_readfirstlane(tid >> 6);
    const int lane = tid & 63;

    const int* mk = meta + (size_t)k * MSTR;             // wave-uniform global meta row
    const int  x0   = -__builtin_amdgcn_readfirstlane(mk[23]);   // slot of s=0 (cmin<=0)
    const int  cmax =  __builtin_amdgcn_readfirstlane(mk[24]);
    const int  nj   =  __builtin_amdgcn_readfirstlane(mk[0]);
    const int  lout = l_out[k];
    const float biasf = bias[k];
    const int  uend = min(WSLOT, lout + 63 + cmax + x0 + 1);     // max touched slot + 1

    // ---- stage: zero only needed pads, then copy 512 real slots (all b128) ----
    float4* xs4 = reinterpret_cast<float4*>(xs_u);
    const float4 z4 = make_float4(0.f, 0.f, 0.f, 0.f);
    for (int i = tid; i < x0; i += 256) xs4[i] = z4;
    for (int i = x0 + SEQ + tid; i < uend; i += 256) xs4[i] = z4;
    const float4* src = reinterpret_cast<const float4*>(xt + (size_t)grp * SEQ * NBB);
    xs4[x0 + tid]       = src[tid];
    xs4[x0 + 256 + tid] = src[256 + tid];
    __syncthreads();

    const unsigned ctermb = h2b(__float2half2_rn(biasf * 16384.f));

    __half2 mx2[4], ct2[4];
    const char* xsc = reinterpret_cast<const char*>(xs_u);
    if (nj <= 7)      conv_body<7 >(xsc, mk, lout, x0, wave, lane, ctermb, mx2, ct2);
    else if (nj <= 9) conv_body<9 >(xsc, mk, lout, x0, wave, lane, ctermb, mx2, ct2);
    else              conv_body<11>(xsc, mk, lout, x0, wave, lane, ctermb, mx2, ct2);

    // ---- 64-lane reduce on the VALU pipe (DPP); lane 63 writes one b128 each ----
    unsigned um[4], uc[4];
#pragma unroll
    for (int m = 0; m < 4; ++m) {
        um[m] = dpp_redmax(h2b(mx2[m]));
        uc[m] = dpp_redadd(h2b(ct2[m]));
    }
    if (lane == 63) {
        *reinterpret_cast<uint4*>(&redm[wave][0]) = make_uint4(um[0], um[1], um[2], um[3]);
        *reinterpret_cast<uint4*>(&redc[wave][0]) = make_uint4(uc[0], uc[1], uc[2], uc[3]);
    }
    __syncthreads();

    if (tid < 16) {
        const int bl = tid >> 1, kind = tid & 1;     // batch-in-group, {max,ppv}
        const int m = bl >> 1, hi = bl & 1;
        const int b = grp * NBB + bl;
        if (kind == 0) {
            float v = -FLT_MAX;
#pragma unroll
            for (int wv = 0; wv < 4; ++wv) {
                const __half2 h = b2h(redm[wv][m]);
                v = fmaxf(v, hi ? __high2float(h) : __low2float(h));
            }
            out[(size_t)b * (2 * K) + 2 * k] = v + biasf;   // deferred bias
        } else {
            float s = 0.f;
#pragma unroll
            for (int wv = 0; wv < 4; ++wv) {
                const __half2 h = b2h(redc[wv][m]);
                s += hi ? __high2float(h) : __low2float(h);
            }
            out[(size_t)b * (2 * K) + 2 * k + 1] = s / (float)lout;
        }
    }
}

// ======================= launch =======================
extern "C" void kernel_launch(void* const* d_in, const int* in_sizes, int n_in,
                              void* d_out, int out_size, void* d_ws, size_t ws_size,
                              hipStream_t stream)
{
    const float* x    = (const float*)d_in[0];
    const float* w    = (const float*)d_in[1];
    const float* bias = (const float*)d_in[2];
    const int*   idx  = (const int*)d_in[3];
    // d_in[4] = valid (unused: validity derived exactly from the idx ramp)
    const int*   lout = (const int*)d_in[5];
    float* out = (float*)d_out;

    const int K    = in_sizes[2];               // N_KERNELS
    const int maxL = in_sizes[3] / (K * KMAX);  // idx = [K][KMAX][maxL]

    // workspace: meta (K*32 ints) | xt16 (NB*SEQ f16), 256B-aligned split
    int* meta = (int*)d_ws;
    size_t meta_bytes = ((size_t)K * MSTR * sizeof(int) + 255) & ~(size_t)255;
    unsigned short* xt = (unsigned short*)((char*)d_ws + meta_bytes);

    prep_kernel<<<K + 32, 256, 0, stream>>>(x, w, idx, meta, xt, K, maxL);
    rocket_main<<<dim3(K, NGRP), 256, 0, stream>>>(xt, meta, bias, lout, out, K);
}

// Round 12
// 34.271 us; speedup vs baseline: 1.4113x; 1.0960x over previous
//
#include <hip/hip_runtime.h>
#include <hip/hip_fp16.h>
#include <float.h>

constexpr int KMAX  = 11;    // KS_MAX
constexpr int SEQ   = 512;   // SEQ_LEN
constexpr int NB    = 64;    // BATCH
constexpr int NBB   = 8;     // batches per main block (8 groups)
constexpr int NGRP  = NB / NBB;
constexpr int MSTR  = 32;    // meta ints per k: [0]=nj [1..11]=c [12..22]=w2bits [23]=cmin [24]=cmax
constexpr int WSLOT = 1600;  // LDS window slots, 16 B (8 f16) each; slot = s - cmin
                             // span proof: lout+63+(cmax-cmin) <= 1022+63+510 = 1595 < 1600

__device__ __forceinline__ unsigned h2b(__half2 h) { unsigned u; __builtin_memcpy(&u, &h, 4); return u; }
__device__ __forceinline__ __half2  b2h(unsigned u) { __half2 h; __builtin_memcpy(&h, &u, 4); return h; }

// ROCm 7.2 has no __hmax2/__hmin2 — use VOP3P directly.
__device__ __forceinline__ unsigned pkmax(unsigned a, unsigned b) {
    unsigned d; asm("v_pk_max_f16 %0, %1, %2" : "=v"(d) : "v"(a), "v"(b)); return d;
}
__device__ __forceinline__ unsigned pkadd(unsigned a, unsigned b) { return h2b(__hadd2(b2h(a), b2h(b))); }
__device__ __forceinline__ __half2 h2max(__half2 a, __half2 b) { return b2h(pkmax(h2b(a), h2b(b))); }
// fused (a*b+c) with result clamped to [0,1] — the whole count update in one VOP3P
__device__ __forceinline__ unsigned pkfma_clamp(unsigned a, unsigned b, unsigned c) {
    unsigned d; asm("v_pk_fma_f16 %0, %1, %2, %3 clamp" : "=v"(d) : "v"(a), "v"(b), "v"(c)); return d;
}

// DPP lane-exchange (VALU pipe, no LDS). Masked-out rows get `old` (identity).
template<int CTRL>
__device__ __forceinline__ unsigned dppmov(unsigned old, unsigned v) {
    return (unsigned)__builtin_amdgcn_update_dpp((int)old, (int)v, CTRL, 0xF, 0xF, false);
}
constexpr unsigned NEGINF2 = 0xFC00FC00u;   // -inf | -inf (f16 pair)

// Full 64-lane max reduce; result valid in lane 63.
__device__ __forceinline__ unsigned dpp_redmax(unsigned x) {
    x = pkmax(x, dppmov<0xB1 >(NEGINF2, x));  // quad_perm xor1
    x = pkmax(x, dppmov<0x4E >(NEGINF2, x));  // quad_perm xor2
    x = pkmax(x, dppmov<0x141>(NEGINF2, x));  // row_half_mirror
    x = pkmax(x, dppmov<0x140>(NEGINF2, x));  // row_mirror
    x = pkmax(x, dppmov<0x142>(NEGINF2, x));  // row_bcast15
    x = pkmax(x, dppmov<0x143>(NEGINF2, x));  // row_bcast31
    return x;
}
// Full 64-lane sum reduce; result valid in lane 63.
__device__ __forceinline__ unsigned dpp_redadd(unsigned x) {
    x = pkadd(x, dppmov<0xB1 >(0u, x));
    x = pkadd(x, dppmov<0x4E >(0u, x));
    x = pkadd(x, dppmov<0x141>(0u, x));
    x = pkadd(x, dppmov<0x140>(0u, x));
    x = pkadd(x, dppmov<0x142>(0u, x));
    x = pkadd(x, dppmov<0x143>(0u, x));
    return x;
}

// ======================= prep kernel =======================
// blocks [0, K):    derive c_kj from idx ramp, compact nonzero-weight taps (f16-packed)
// blocks [K, K+32): transpose+convert x (NB x SEQ f32) -> xt16[g][s][8] f16
__global__ __launch_bounds__(256)
void prep_kernel(const float* __restrict__ x, const float* __restrict__ w,
                 const int* __restrict__ idx, int* __restrict__ meta,
                 unsigned short* __restrict__ xt, int K, int maxL)
{
    const int tid = threadIdx.x;
    if ((int)blockIdx.x >= K) {
        const int j  = ((int)blockIdx.x - K) * 256 + tid;   // 0..8191
        const int b  = j >> 7;                              // 0..63
        const int s4 = j & 127;                             // 0..127
        const float4 v = reinterpret_cast<const float4*>(x)[b * (SEQ / 4) + s4];
        const int g = b >> 3, bl = b & 7;
        unsigned short* dst = xt + ((size_t)g * SEQ + s4 * 4) * NBB + bl;
        __half h;
        h = __float2half_rn(v.x); __builtin_memcpy(&dst[0 * NBB], &h, 2);
        h = __float2half_rn(v.y); __builtin_memcpy(&dst[1 * NBB], &h, 2);
        h = __float2half_rn(v.z); __builtin_memcpy(&dst[2 * NBB], &h, 2);
        h = __float2half_rn(v.w); __builtin_memcpy(&dst[3 * NBB], &h, 2);
        return;
    }

    __shared__ int c_sh[KMAX];
    const int k = blockIdx.x, wave = tid >> 6, lane = tid & 63;

    // idx[k,j,t] = clip(t + c, 0, 511): first interior value (0 < v < 511) gives c = v - t.
    for (int j = wave; j < KMAX; j += 4) {
        const int* row = idx + ((size_t)k * KMAX + j) * (size_t)maxL;
        int c = 0;
        for (int base = 0; base < maxL; base += 64) {
            const int t = base + lane;
            const int v = (t < maxL) ? row[t] : 0;
            const bool interior = (v > 0) && (v < SEQ - 1);
            const unsigned long long mb = __ballot(interior);
            if (mb != 0ull) {
                const int fl = __builtin_ctzll(mb);
                c = __shfl(v, fl) - (base + fl);
                break;
            }
        }
        if (lane == 0) c_sh[j] = c;
    }
    __syncthreads();

    if (tid == 0) {
        int* mk = meta + (size_t)k * MSTR;
        int n = 0, cmin = 0, cmax = 0;
        for (int j = 0; j < KMAX; ++j) {
            const float wj = w[(size_t)k * KMAX + j];
            if (wj != 0.0f) {
                const int c = c_sh[j];
                mk[1 + n] = c;
                __half hw = __float2half_rn(wj);
                unsigned short ub; __builtin_memcpy(&ub, &hw, 2);
                mk[12 + n] = (unsigned)ub | ((unsigned)ub << 16);
                cmin = min(cmin, c); cmax = max(cmax, c);
                ++n;
            }
        }
        for (int jj = n; jj < KMAX; ++jj) { mk[1 + jj] = 0; mk[12 + jj] = 0; }   // harmless pads
        mk[0]  = n;
        mk[23] = cmin;
        mk[24] = cmax;
    }
}

// ======================= main kernel =======================
// grid (K, 8): block = (kernel k, 8-batch group). 256 threads = 4 waves.
// LDS window: slot = s - cmin, 8 f16 batches per slot (16 B). Zeros outside x's
// [0,512) range => out-of-range taps contribute exactly 0 (== reference's mask).
// Branchless conv: chunk ic handled by wave ic&3 at unroll-step ic>>2; all NJ
// ds_read_b128 issue back-to-back with compile-time offset immediates (it*4096).
// NOTE __launch_bounds__(256,4): (256,6) capped VGPRs at ~42 (measured 40),
// forcing the 11-read batch to split into tiny groups with lgkmcnt waits —
// serializing LDS latency. 128-VGPR cap restores full read batching.
template<int NJ>
__device__ __forceinline__ void conv_body(
    const char* __restrict__ xsc, const int* __restrict__ msh,
    int lout, int x0, int wave, int lane, unsigned ctermb,
    __half2 (&mx2)[4], __half2 (&ct2)[4])
{
    const __half2 zero2 = __float2half2_rn(0.f);
    const __half2 nbig2 = __float2half2_rn(-65504.f);
    const unsigned C4b  = 0x74007400u;   // f16 pair {2^14, 2^14}

    int addr[NJ]; __half2 wr[NJ];
#pragma unroll
    for (int j = 0; j < NJ; ++j) {
        const int c = __builtin_amdgcn_readfirstlane(msh[1 + j]);
        wr[j]   = b2h((unsigned)__builtin_amdgcn_readfirstlane(msh[12 + j]));
        addr[j] = (wave * 64 + lane + c + x0) * 16;
    }
#pragma unroll
    for (int m = 0; m < 4; ++m) { mx2[m] = nbig2; ct2[m] = zero2; }

#pragma unroll
    for (int it = 0; it < 4; ++it) {
        const int tb = wave * 64 + it * 256;
        if (tb + 64 <= lout) {             // wave-uniform SALU guard, full chunk
            uint4 d[NJ];
#pragma unroll
            for (int j = 0; j < NJ; ++j)
                d[j] = *reinterpret_cast<const uint4*>(xsc + addr[j] + it * 4096);
            __half2 a[4] = {zero2, zero2, zero2, zero2};
#pragma unroll
            for (int j = 0; j < NJ; ++j) {
                a[0] = __hfma2(wr[j], b2h(d[j].x), a[0]);
                a[1] = __hfma2(wr[j], b2h(d[j].y), a[1]);
                a[2] = __hfma2(wr[j], b2h(d[j].z), a[2]);
                a[3] = __hfma2(wr[j], b2h(d[j].w), a[3]);
            }
#pragma unroll
            for (int m = 0; m < 4; ++m) {
                mx2[m] = h2max(mx2[m], a[m]);
                ct2[m] = b2h(pkadd(h2b(ct2[m]), pkfma_clamp(h2b(a[m]), C4b, ctermb)));
            }
        }
    }

    const int rem = lout & 63;
    if (rem) {                              // partial chunk pc, owned by wave pc&3
        const int pc = lout >> 6;
        if ((pc & 3) == wave) {
            const int off = (pc >> 2) << 12;
            uint4 d[NJ];
#pragma unroll
            for (int j = 0; j < NJ; ++j)
                d[j] = *reinterpret_cast<const uint4*>(xsc + addr[j] + off);
            __half2 a[4] = {zero2, zero2, zero2, zero2};
#pragma unroll
            for (int j = 0; j < NJ; ++j) {
                a[0] = __hfma2(wr[j], b2h(d[j].x), a[0]);
                a[1] = __hfma2(wr[j], b2h(d[j].y), a[1]);
                a[2] = __hfma2(wr[j], b2h(d[j].z), a[2]);
                a[3] = __hfma2(wr[j], b2h(d[j].w), a[3]);
            }
            const bool tm = lane < rem;
#pragma unroll
            for (int m = 0; m < 4; ++m) {
                a[m] = tm ? a[m] : nbig2;   // -65504*2^14 -> -inf -> clamp -> 0
                mx2[m] = h2max(mx2[m], a[m]);
                ct2[m] = b2h(pkadd(h2b(ct2[m]), pkfma_clamp(h2b(a[m]), C4b, ctermb)));
            }
        }
    }
}

__global__ __launch_bounds__(256, 4)
void rocket_main(const unsigned short* __restrict__ xt, const int* __restrict__ meta,
                 const float* __restrict__ bias, const int* __restrict__ l_out,
                 float* __restrict__ out, int K)
{
    __shared__ __align__(16) unsigned xs_u[WSLOT * 4];   // 25600 B window
    __shared__ unsigned redm[4][4], redc[4][4];
    __shared__ int msh[MSTR];

    const int k    = blockIdx.x;
    const int grp  = blockIdx.y;
    const int tid  = threadIdx.x;
    const int wave = __builtin_amdgcn_readfirstlane(tid >> 6);
    const int lane = tid & 63;

    if (tid < MSTR) msh[tid] = meta[(size_t)k * MSTR + tid];
    __syncthreads();

    const int   x0    = -msh[23];                   // slot of s=0 (cmin <= 0)
    const int   lout  = l_out[k];
    const float biasf = bias[k];
    const int   uend  = min(WSLOT, lout + 63 + msh[24] + x0 + 1);   // max touched slot + 1

    // ---- stage: zero only the needed pads, then copy 512 real slots (all b128) ----
    float4* xs4 = reinterpret_cast<float4*>(xs_u);
    const float4 z4 = make_float4(0.f, 0.f, 0.f, 0.f);
    for (int i = tid; i < x0; i += 256) xs4[i] = z4;
    for (int i = x0 + SEQ + tid; i < uend; i += 256) xs4[i] = z4;
    const float4* src = reinterpret_cast<const float4*>(xt + (size_t)grp * SEQ * NBB);
    xs4[x0 + tid]       = src[tid];
    xs4[x0 + 256 + tid] = src[256 + tid];
    __syncthreads();

    const int      nj     = __builtin_amdgcn_readfirstlane(msh[0]);
    const unsigned ctermb = h2b(__float2half2_rn(biasf * 16384.f));

    __half2 mx2[4], ct2[4];
    const char* xsc = reinterpret_cast<const char*>(xs_u);
    if (nj <= 7)      conv_body<7 >(xsc, msh, lout, x0, wave, lane, ctermb, mx2, ct2);
    else if (nj <= 9) conv_body<9 >(xsc, msh, lout, x0, wave, lane, ctermb, mx2, ct2);
    else              conv_body<11>(xsc, msh, lout, x0, wave, lane, ctermb, mx2, ct2);

    // ---- 64-lane reduce on the VALU pipe (DPP); lane 63 holds the result ----
    unsigned um[4], uc[4];
#pragma unroll
    for (int m = 0; m < 4; ++m) {
        um[m] = dpp_redmax(h2b(mx2[m]));
        uc[m] = dpp_redadd(h2b(ct2[m]));
    }
    if (lane == 63) {
#pragma unroll
        for (int m = 0; m < 4; ++m) { redm[wave][m] = um[m]; redc[wave][m] = uc[m]; }
    }
    __syncthreads();

    if (tid < 16) {
        const int bl = tid >> 1, kind = tid & 1;     // batch-in-group, {max,ppv}
        const int m = bl >> 1, hi = bl & 1;
        const int b = grp * NBB + bl;
        if (kind == 0) {
            float v = -FLT_MAX;
#pragma unroll
            for (int wv = 0; wv < 4; ++wv) {
                const __half2 h = b2h(redm[wv][m]);
                v = fmaxf(v, hi ? __high2float(h) : __low2float(h));
            }
            out[(size_t)b * (2 * K) + 2 * k] = v + biasf;   // deferred bias
        } else {
            float s = 0.f;
#pragma unroll
            for (int wv = 0; wv < 4; ++wv) {
                const __half2 h = b2h(redc[wv][m]);
                s += hi ? __high2float(h) : __low2float(h);
            }
            out[(size_t)b * (2 * K) + 2 * k + 1] = s / (float)lout;
        }
    }
}

// ======================= launch =======================
extern "C" void kernel_launch(void* const* d_in, const int* in_sizes, int n_in,
                              void* d_out, int out_size, void* d_ws, size_t ws_size,
                              hipStream_t stream)
{
    const float* x    = (const float*)d_in[0];
    const float* w    = (const float*)d_in[1];
    const float* bias = (const float*)d_in[2];
    const int*   idx  = (const int*)d_in[3];
    // d_in[4] = valid (unused: validity derived exactly from the idx ramp)
    const int*   lout = (const int*)d_in[5];
    float* out = (float*)d_out;

    const int K    = in_sizes[2];               // N_KERNELS
    const int maxL = in_sizes[3] / (K * KMAX);  // idx = [K][KMAX][maxL]

    // workspace: meta (K*32 ints) | xt16 (NB*SEQ f16), 256B-aligned split
    int* meta = (int*)d_ws;
    size_t meta_bytes = ((size_t)K * MSTR * sizeof(int) + 255) & ~(size_t)255;
    unsigned short* xt = (unsigned short*)((char*)d_ws + meta_bytes);

    prep_kernel<<<K + 32, 256, 0, stream>>>(x, w, idx, meta, xt, K, maxL);
    rocket_main<<<dim3(K, NGRP), 256, 0, stream>>>(xt, meta, bias, lout, out, K);
}

// Round 13
// 31.207 us; speedup vs baseline: 1.5498x; 1.0982x over previous
//
#include <hip/hip_runtime.h>
#include <hip/hip_fp16.h>
#include <float.h>

constexpr int KMAX  = 11;    // KS_MAX
constexpr int SEQ   = 512;   // SEQ_LEN
constexpr int NB    = 64;    // BATCH
constexpr int NBB   = 8;     // batches per main block (8 groups)
constexpr int NGRP  = NB / NBB;
constexpr int KPB   = 4;     // kernels per block = 1 per wave
constexpr int MSTR  = 32;    // meta ints per k: [0]=nj [1..11]=c [12..22]=w2bits
constexpr int SBASE = 512;   // fixed window: slot = s + 512
constexpr int WSLOT = 1600;  // s in [-512, 1088). Bound proof: pad>0 => c<=2 and
                             // lout<=1022 => s_max = lout+62+2 = 1086; pad=0 =>
                             // lout+c_max = 512 => s_max = 574. s_min = -2*pad >= -510.

__device__ __forceinline__ unsigned h2b(__half2 h) { unsigned u; __builtin_memcpy(&u, &h, 4); return u; }
__device__ __forceinline__ __half2  b2h(unsigned u) { __half2 h; __builtin_memcpy(&h, &u, 4); return h; }

// ROCm 7.2 has no __hmax2/__hmin2 — use VOP3P directly.
__device__ __forceinline__ unsigned pkmax(unsigned a, unsigned b) {
    unsigned d; asm("v_pk_max_f16 %0, %1, %2" : "=v"(d) : "v"(a), "v"(b)); return d;
}
__device__ __forceinline__ unsigned pkadd(unsigned a, unsigned b) { return h2b(__hadd2(b2h(a), b2h(b))); }
__device__ __forceinline__ __half2 h2max(__half2 a, __half2 b) { return b2h(pkmax(h2b(a), h2b(b))); }
// fused (a*b+c) clamped to [0,1] — the whole count update in one VOP3P
__device__ __forceinline__ unsigned pkfma_clamp(unsigned a, unsigned b, unsigned c) {
    unsigned d; asm("v_pk_fma_f16 %0, %1, %2, %3 clamp" : "=v"(d) : "v"(a), "v"(b), "v"(c)); return d;
}

template<int CTRL>
__device__ __forceinline__ unsigned dppmov(unsigned old, unsigned v) {
    return (unsigned)__builtin_amdgcn_update_dpp((int)old, (int)v, CTRL, 0xF, 0xF, false);
}
constexpr unsigned NEGINF2 = 0xFC00FC00u;   // -inf | -inf (f16 pair)

__device__ __forceinline__ unsigned dpp_redmax(unsigned x) {
    x = pkmax(x, dppmov<0xB1 >(NEGINF2, x));  // quad_perm xor1
    x = pkmax(x, dppmov<0x4E >(NEGINF2, x));  // quad_perm xor2
    x = pkmax(x, dppmov<0x141>(NEGINF2, x));  // row_half_mirror
    x = pkmax(x, dppmov<0x140>(NEGINF2, x));  // row_mirror
    x = pkmax(x, dppmov<0x142>(NEGINF2, x));  // row_bcast15
    x = pkmax(x, dppmov<0x143>(NEGINF2, x));  // row_bcast31
    return x;                                  // lane 63 valid
}
__device__ __forceinline__ unsigned dpp_redadd(unsigned x) {
    x = pkadd(x, dppmov<0xB1 >(0u, x));
    x = pkadd(x, dppmov<0x4E >(0u, x));
    x = pkadd(x, dppmov<0x141>(0u, x));
    x = pkadd(x, dppmov<0x140>(0u, x));
    x = pkadd(x, dppmov<0x142>(0u, x));
    x = pkadd(x, dppmov<0x143>(0u, x));
    return x;                                  // lane 63 valid
}

// ======================= prep kernel (unchanged from R12) =======================
__global__ __launch_bounds__(256)
void prep_kernel(const float* __restrict__ x, const float* __restrict__ w,
                 const int* __restrict__ idx, int* __restrict__ meta,
                 unsigned short* __restrict__ xt, int K, int maxL)
{
    const int tid = threadIdx.x;
    if ((int)blockIdx.x >= K) {
        const int j  = ((int)blockIdx.x - K) * 256 + tid;   // 0..8191
        const int b  = j >> 7, s4 = j & 127;
        const float4 v = reinterpret_cast<const float4*>(x)[b * (SEQ / 4) + s4];
        const int g = b >> 3, bl = b & 7;
        unsigned short* dst = xt + ((size_t)g * SEQ + s4 * 4) * NBB + bl;
        __half h;
        h = __float2half_rn(v.x); __builtin_memcpy(&dst[0 * NBB], &h, 2);
        h = __float2half_rn(v.y); __builtin_memcpy(&dst[1 * NBB], &h, 2);
        h = __float2half_rn(v.z); __builtin_memcpy(&dst[2 * NBB], &h, 2);
        h = __float2half_rn(v.w); __builtin_memcpy(&dst[3 * NBB], &h, 2);
        return;
    }

    __shared__ int c_sh[KMAX];
    const int k = blockIdx.x, wave = tid >> 6, lane = tid & 63;

    // idx[k,j,t] = clip(t + c, 0, 511): first interior value (0 < v < 511) gives c = v - t.
    for (int j = wave; j < KMAX; j += 4) {
        const int* row = idx + ((size_t)k * KMAX + j) * (size_t)maxL;
        int c = 0;
        for (int base = 0; base < maxL; base += 64) {
            const int t = base + lane;
            const int v = (t < maxL) ? row[t] : 0;
            const bool interior = (v > 0) && (v < SEQ - 1);
            const unsigned long long mb = __ballot(interior);
            if (mb != 0ull) {
                const int fl = __builtin_ctzll(mb);
                c = __shfl(v, fl) - (base + fl);
                break;
            }
        }
        if (lane == 0) c_sh[j] = c;
    }
    __syncthreads();

    if (tid == 0) {
        int* mk = meta + (size_t)k * MSTR;
        int n = 0;
        for (int j = 0; j < KMAX; ++j) {
            const float wj = w[(size_t)k * KMAX + j];
            if (wj != 0.0f) {
                mk[1 + n] = c_sh[j];
                __half hw = __float2half_rn(wj);
                unsigned short ub; __builtin_memcpy(&ub, &hw, 2);
                mk[12 + n] = (unsigned)ub | ((unsigned)ub << 16);
                ++n;
            }
        }
        for (int jj = n; jj < KMAX; ++jj) { mk[1 + jj] = 0; mk[12 + jj] = 0; }   // in-window, w=0
        mk[0] = n;
    }
}

// ======================= main kernel =======================
// grid (K/4, 8): block = (4 kernels, 8-batch group). 256 threads = 4 waves.
// Fixed k-independent window (slot = s+512, zeros outside s in [0,512)) staged
// once; ONE barrier; then each wave owns kernel k = kbase+wave end-to-end:
// meta via one coalesced 128B wave-load + readlane (no LDS, no barrier), conv
// over ALL chunks of k (4x-unrolled immediate DS offsets), DPP reduce, lane 63
// stores the 16 outputs. Zero cross-wave coupling after the staging barrier.
template<int NJ>
__device__ __forceinline__ void conv_wave(
    const char* __restrict__ xsc, int mrow, int lout, int lane, unsigned ctermb,
    unsigned (&um)[4], unsigned (&uc)[4])
{
    const __half2 zero2 = __float2half2_rn(0.f);
    const __half2 nbig2 = __float2half2_rn(-65504.f);
    const unsigned C4b  = 0x74007400u;   // f16 pair {2^14, 2^14}

    int addr[NJ]; __half2 wr[NJ];
#pragma unroll
    for (int j = 0; j < NJ; ++j) {
        const int c = __builtin_amdgcn_readlane(mrow, 1 + j);
        wr[j]   = b2h((unsigned)__builtin_amdgcn_readlane(mrow, 12 + j));
        addr[j] = (lane + c + SBASE) * 16;
    }
    __half2 mx2[4], ct2[4];
#pragma unroll
    for (int m = 0; m < 4; ++m) { mx2[m] = nbig2; ct2[m] = zero2; }

    const int nfull = lout >> 6;
    const int ng4   = nfull >> 2;

    for (int g = 0; g < ng4; ++g) {       // groups of 4 full chunks, immediate offsets
#pragma unroll
        for (int u = 0; u < 4; ++u) {
            uint4 d[NJ];
#pragma unroll
            for (int j = 0; j < NJ; ++j)
                d[j] = *reinterpret_cast<const uint4*>(xsc + addr[j] + u * 1024);
            __half2 a[4] = {zero2, zero2, zero2, zero2};
#pragma unroll
            for (int j = 0; j < NJ; ++j) {
                a[0] = __hfma2(wr[j], b2h(d[j].x), a[0]);
                a[1] = __hfma2(wr[j], b2h(d[j].y), a[1]);
                a[2] = __hfma2(wr[j], b2h(d[j].z), a[2]);
                a[3] = __hfma2(wr[j], b2h(d[j].w), a[3]);
            }
#pragma unroll
            for (int m = 0; m < 4; ++m) {
                mx2[m] = h2max(mx2[m], a[m]);
                ct2[m] = b2h(pkadd(h2b(ct2[m]), pkfma_clamp(h2b(a[m]), C4b, ctermb)));
            }
        }
#pragma unroll
        for (int j = 0; j < NJ; ++j) addr[j] += 4096;
    }
    for (int u = 0; u < (nfull & 3); ++u) {   // leftover full chunks
        uint4 d[NJ];
#pragma unroll
        for (int j = 0; j < NJ; ++j)
            d[j] = *reinterpret_cast<const uint4*>(xsc + addr[j]);
        __half2 a[4] = {zero2, zero2, zero2, zero2};
#pragma unroll
        for (int j = 0; j < NJ; ++j) {
            a[0] = __hfma2(wr[j], b2h(d[j].x), a[0]);
            a[1] = __hfma2(wr[j], b2h(d[j].y), a[1]);
            a[2] = __hfma2(wr[j], b2h(d[j].z), a[2]);
            a[3] = __hfma2(wr[j], b2h(d[j].w), a[3]);
        }
#pragma unroll
        for (int m = 0; m < 4; ++m) {
            mx2[m] = h2max(mx2[m], a[m]);
            ct2[m] = b2h(pkadd(h2b(ct2[m]), pkfma_clamp(h2b(a[m]), C4b, ctermb)));
        }
#pragma unroll
        for (int j = 0; j < NJ; ++j) addr[j] += 1024;
    }
    const int rem = lout & 63;
    if (rem) {                                 // straddle chunk, lane-masked
        uint4 d[NJ];
#pragma unroll
        for (int j = 0; j < NJ; ++j)
            d[j] = *reinterpret_cast<const uint4*>(xsc + addr[j]);
        __half2 a[4] = {zero2, zero2, zero2, zero2};
#pragma unroll
        for (int j = 0; j < NJ; ++j) {
            a[0] = __hfma2(wr[j], b2h(d[j].x), a[0]);
            a[1] = __hfma2(wr[j], b2h(d[j].y), a[1]);
            a[2] = __hfma2(wr[j], b2h(d[j].z), a[2]);
            a[3] = __hfma2(wr[j], b2h(d[j].w), a[3]);
        }
        const bool tm = lane < rem;
#pragma unroll
        for (int m = 0; m < 4; ++m) {
            a[m] = tm ? a[m] : nbig2;          // -65504*2^14 -> -inf -> clamp -> 0
            mx2[m] = h2max(mx2[m], a[m]);
            ct2[m] = b2h(pkadd(h2b(ct2[m]), pkfma_clamp(h2b(a[m]), C4b, ctermb)));
        }
    }

#pragma unroll
    for (int m = 0; m < 4; ++m) {
        um[m] = dpp_redmax(h2b(mx2[m]));
        uc[m] = dpp_redadd(h2b(ct2[m]));
    }
}

__global__ __launch_bounds__(256, 4)
void rocket_main(const unsigned short* __restrict__ xt, const int* __restrict__ meta,
                 const float* __restrict__ bias, const int* __restrict__ l_out,
                 float* __restrict__ out, int K)
{
    __shared__ __align__(16) unsigned xs_u[WSLOT * 4];   // 25600 B fixed window

    const int kbase = (int)blockIdx.x * KPB;
    const int grp   = blockIdx.y;
    const int tid   = threadIdx.x;
    const int wave  = tid >> 6, lane = tid & 63;

    // ---- stage fixed window (zeros outside s in [0,512)); conflict-free b128 ----
    float4* xs4 = reinterpret_cast<float4*>(xs_u);
    const float4* src = reinterpret_cast<const float4*>(xt + (size_t)grp * SEQ * NBB);
    const float4 z4 = make_float4(0.f, 0.f, 0.f, 0.f);
    for (int i = tid; i < WSLOT; i += 256) {
        const int s = i - SBASE;
        xs4[i] = ((unsigned)s < (unsigned)SEQ) ? src[s] : z4;
    }
    __syncthreads();

    const int k = kbase + wave;
    if (k >= K) return;

    // ---- per-wave k: meta row as one coalesced 128B load + readlane ----
    const int mrow  = meta[(size_t)k * MSTR + (lane & 31)];
    const int nj    = __builtin_amdgcn_readlane(mrow, 0);
    const int lout  = __builtin_amdgcn_readfirstlane(l_out[k]);
    const float biasf = __int_as_float(__builtin_amdgcn_readfirstlane(__float_as_int(bias[k])));
    const unsigned ctermb = h2b(__float2half2_rn(biasf * 16384.f));

    unsigned um[4], uc[4];
    const char* xsc = reinterpret_cast<const char*>(xs_u);
    if (nj <= 7)      conv_wave<7 >(xsc, mrow, lout, lane, ctermb, um, uc);
    else if (nj <= 9) conv_wave<9 >(xsc, mrow, lout, lane, ctermb, um, uc);
    else              conv_wave<11>(xsc, mrow, lout, lane, ctermb, um, uc);

    // ---- lane 63 finalizes: 8 batches x {max, ppv} ----
    if (lane == 63) {
        const float loutf = (float)lout;
#pragma unroll
        for (int m = 0; m < 4; ++m) {
            const __half2 hm = b2h(um[m]);
            const __half2 hc = b2h(uc[m]);
            float* o0 = out + (size_t)(grp * NBB + 2 * m) * (2 * K) + 2 * k;
            o0[0] = __low2float(hm) + biasf;           // deferred bias
            o0[1] = __low2float(hc) / loutf;
            float* o1 = o0 + 2 * K;
            o1[0] = __high2float(hm) + biasf;
            o1[1] = __high2float(hc) / loutf;
        }
    }
}

// ======================= launch =======================
extern "C" void kernel_launch(void* const* d_in, const int* in_sizes, int n_in,
                              void* d_out, int out_size, void* d_ws, size_t ws_size,
                              hipStream_t stream)
{
    const float* x    = (const float*)d_in[0];
    const float* w    = (const float*)d_in[1];
    const float* bias = (const float*)d_in[2];
    const int*   idx  = (const int*)d_in[3];
    // d_in[4] = valid (unused: validity derived exactly from the idx ramp)
    const int*   lout = (const int*)d_in[5];
    float* out = (float*)d_out;

    const int K    = in_sizes[2];               // N_KERNELS
    const int maxL = in_sizes[3] / (K * KMAX);  // idx = [K][KMAX][maxL]

    // workspace: meta (K*32 ints) | xt16 (NB*SEQ f16), 256B-aligned split
    int* meta = (int*)d_ws;
    size_t meta_bytes = ((size_t)K * MSTR * sizeof(int) + 255) & ~(size_t)255;
    unsigned short* xt = (unsigned short*)((char*)d_ws + meta_bytes);

    prep_kernel<<<K + 32, 256, 0, stream>>>(x, w, idx, meta, xt, K, maxL);
    rocket_main<<<dim3((K + KPB - 1) / KPB, NGRP), 256, 0, stream>>>(xt, meta, bias, lout, out, K);
}